// Round 5
// baseline (340.107 us; speedup 1.0000x reference)
//
#include <hip/hip_runtime.h>
#include <math.h>

#define BL 16384
#define D  512
#define K  4096
#define NCHB 8          // 64-k chunks: 512 k / 64
#define XLOFF 8388608   // halves offset of xl' stream inside d_out region

// ---- ws layout (bytes) ----
#define OFF_C2    0                // 4096 f
#define OFF_X2    (16<<10)         // 16384 f (aliased as loss partials after rescore)
#define OFF_CNT   (80<<10)         // 4096 f
#define OFF_AVGC  (96<<10)         // 4096 f
#define OFF_SCAL  (112<<10)        // N float @+8
#define OFF_IDX16 (116<<10)        // 16384 u16
#define OFF_KEYS  (160<<10)        // 16384 u64
#define OFF_CAND  (288<<10)        // 16384*8 u16
#define OFF_CBP   (576<<10)        // cb' 8*4096*128 B = 4.19 MB; cbn (8 MB) reuses after argmin
#define OFF_CBN_FB (256<<10)       // fallback cbn

typedef _Float16 f16x8 __attribute__((ext_vector_type(8)));
typedef float    f32x4 __attribute__((ext_vector_type(4)));
#define MFMA16(a,b,c) __builtin_amdgcn_mfma_f32_16x16x32_f16(a,b,c,0,0,0)

// ================= bit-exact helpers (feed exact rescore — DO NOT TOUCH) ====

__global__ void rowsq_all(const float* __restrict__ x, const float* __restrict__ cb,
                          float* __restrict__ x2, float* __restrict__ c2)
{
    int b    = blockIdx.x;
    int lane = threadIdx.x;              // 64
    const float* p; float* o; int row;
    if (b < K) { p = cb; o = c2; row = b; }
    else       { p = x;  o = x2; row = b - K; }
    p += (size_t)row * D;
    float s = 0.f;
#pragma unroll
    for (int j = 0; j < D / 64; ++j) {
        float v = p[lane + j * 64];
        s = fmaf(v, v, s);
    }
#pragma unroll
    for (int off = 32; off > 0; off >>= 1)
        s += __shfl_down(s, off, 64);
    if (lane == 0) o[row] = s;
}

// exact rescore, bit-identical arithmetic to round-1 (sequential fmaf k=0..511);
// also emits counts + compact u16 indices.
__global__ __launch_bounds__(256) void rescore_kernel(
    const float* __restrict__ x, const float* __restrict__ cb,
    const float* __restrict__ x2, const float* __restrict__ c2,
    const unsigned short* __restrict__ cand,
    unsigned long long* __restrict__ keys,
    float* __restrict__ counts, unsigned short* __restrict__ idx16)
{
    int t = blockIdx.x * 256 + threadIdx.x;  // 131072
    int row = t >> 3, ci = t & 7;
    int idx = cand[(size_t)row * 8 + ci];
    const float* xp = x  + (size_t)row * D;
    const float* cp = cb + (size_t)idx * D;
    float acc = 0.f;
#pragma unroll 4
    for (int k0 = 0; k0 < D; k0 += 4) {
        float4 xv = *(const float4*)(xp + k0);
        float4 cv = *(const float4*)(cp + k0);
        acc = fmaf(xv.x, cv.x, acc);
        acc = fmaf(xv.y, cv.y, acc);
        acc = fmaf(xv.z, cv.z, acc);
        acc = fmaf(xv.w, cv.w, acc);
    }
    float wv = x2[row] - 2.0f * acc;
    float dd = wv + c2[idx];
    unsigned long long key =
        ((unsigned long long)__float_as_uint(dd) << 12) | (unsigned long long)idx;
#pragma unroll
    for (int m = 1; m < 8; m <<= 1) {
        unsigned long long o = __shfl_xor(key, m, 64);
        key = o < key ? o : key;
    }
    if ((t & 7) == 0) {
        keys[row] = key;
        int kf = (int)(key & 0xFFFULL);
        idx16[row] = (unsigned short)kf;
        atomicAdd(&counts[kf], 1.0f);
    }
}

// ================= primary path ============================================

__device__ __forceinline__ void load_lds16(const unsigned short* g, unsigned short* l) {
    __builtin_amdgcn_global_load_lds(
        (const __attribute__((address_space(1))) unsigned int*)(g),
        (__attribute__((address_space(3))) unsigned int*)(l), 16, 0, 0);
}

// fp32 -> fp16 hi/lo streams. 64-k chunks, 128 B rows, 8 granules x 16 B,
// phys granule p = g ^ (row&7) (g = k-group 0..7, k = 64c + 8g .. +7).
// x: hi stream at xp[0..], lo stream at xp[XLOFF..]. cb: hi only.
__global__ __launch_bounds__(256) void split_interleave(
    const float* __restrict__ x, const float* __restrict__ cb,
    unsigned short* __restrict__ xp, unsigned short* __restrict__ cbp)
{
    int gw   = blockIdx.x * 4 + (threadIdx.x >> 6);  // 0..20479
    int lane = threadIdx.x & 63;
    int rl   = lane >> 3;
    int p    = lane & 7;
    const float* src; int nr, c, r0; bool isX;
    if (gw < 16384) { c = gw >> 11; r0 = (gw & 2047) * 8; src = x;  nr = BL; isX = true; }
    else { int lw = gw - 16384; c = lw >> 9; r0 = (lw & 511) * 8; src = cb; nr = K; isX = false; }
    int r = r0 + rl;
    int g = p ^ rl;                  // r&7 == rl
    const float* sp = src + (size_t)r * D + c * 64 + g * 8;
    float4 f0 = *(const float4*)sp, f1 = *(const float4*)(sp + 4);
    float f[8] = {f0.x,f0.y,f0.z,f0.w,f1.x,f1.y,f1.z,f1.w};
    __align__(16) _Float16 oh[8], ol[8];
#pragma unroll
    for (int i = 0; i < 8; ++i) {
        _Float16 h = (_Float16)f[i];           // RNE
        oh[i] = h;
        ol[i] = (_Float16)(f[i] - (float)h);   // exact residual -> RNE fp16
    }
    size_t off = ((size_t)(c * nr + r) * 8 + p) * 8;   // halves
    if (isX) {
        *(uint4*)(xp + off)         = *(const uint4*)oh;
        *(uint4*)(xp + XLOFF + off) = *(const uint4*)ol;
    } else {
        *(uint4*)(cbp + off) = *(const uint4*)oh;
    }
}

// MFMA approx distance + per-split top-2 — round-4 geometry (4 waves,
// 128 rows x 1024 codes, wave tile 64x128, 0.25 ds_read/MFMA, 2 blocks/CU)
// with the 64-k chunk split into two 32-k sub-chunks (32 KB each) so the
// staging DOUBLE-BUFFERS in 64 KB: per sub-chunk it: issue DMA(it+1) into
// the other buffer, compute it, one __syncthreads at the bottom. The drain
// now targets loads issued a full ~2400-cyc compute earlier -> exposure ~0
// (vs round-4's issue-then-drain). DMA de-swizzles at the SOURCE (per-lane
// global addr p=(4h+j)^(row&7), linear LDS dest), reads use plain
// row*64+q*16. Accumulation order identical to round-4 -> bit-identical acc.
__global__ __launch_bounds__(256, 2) void argmin_mfma(
    const unsigned short* __restrict__ xp, const unsigned short* __restrict__ cbp,
    const float* __restrict__ x2, const float* __restrict__ c2,
    unsigned short* __restrict__ cand)
{
    __shared__ __align__(16) unsigned short buf[2 * 16384];  // 2 x 32 KiB dbuf
    __shared__ __align__(16) float c2s[1024];                // 4 KiB
    __shared__ float x2s[128];

    // u16 offsets inside one buffer: A-hi 0 (8KB), A-lo 4096 (8KB), B 8192 (16KB)

    const int tid = threadIdx.x;        // 0..255
    const int l   = tid & 63;
    const int w   = tid >> 6;           // 0..3
    const int wm  = w >> 1;             // 0..1  row half
    const int wn  = w & 1;              // 0..1  col half (128 cols each)
    const int q   = l >> 4;             // quad -> k-subgroup (granule)
    const int cc  = l & 15;             // row/col lane
    const int row0 = blockIdx.x * 128;
    const int nb   = blockIdx.y * 1024;

    // stash x2/c2 (keeps loop free of stray VMEM)
    if (tid < 128) x2s[tid] = x2[row0 + tid];
#pragma unroll
    for (int j = 0; j < 4; ++j) c2s[j * 256 + tid] = c2[nb + j * 256 + tid];

    // chunk-invariant LDS BYTE offsets (plain layout: [row][granule j])
    int rdA[4], rdB[8];
#pragma unroll
    for (int t = 0; t < 4; ++t)
        rdA[t] = (wm * 64 + t * 16 + cc) * 64 + q * 16;     // < 8192
#pragma unroll
    for (int t = 0; t < 8; ++t)
        rdB[t] = (wn * 128 + t * 16 + cc) * 64 + q * 16;    // < 16384

    // stage sub-chunk s (s = n0*16 + c64*2 + h) into buf[s&1].
    // LDS slot [row][j] gets logical granule g=4h+j, i.e. phys p=g^(row&7)
    // at the source. Dest is wave-uniform-base + lane*16B (DMA requirement).
    auto STAGE = [&](int s) {
        const int n0s = s >> 4, c64 = (s >> 1) & 7, h = s & 1;
        unsigned short* d = buf + (s & 1) * 16384;
        const int jr = l & 3, rr = l >> 2;
        const int p  = ((h << 2) | jr) ^ (rr & 7);          // row&7 == rr&7 (16-row aligned)
        const unsigned short* gAh = xp + (((size_t)c64 * BL + row0) << 6);
        const unsigned short* gAl = gAh + XLOFF;
        const unsigned short* gB  = cbp + (((size_t)c64 * K + nb + n0s * 256) << 6);
#pragma unroll
        for (int i = 0; i < 2; ++i) {
            const int rbase = (w + 4 * i) * 16;
            load_lds16(gAh + (size_t)(rbase + rr) * 64 + p * 8,
                       d + (w + 4 * i) * 512 + l * 8);
            load_lds16(gAl + (size_t)(rbase + rr) * 64 + p * 8,
                       d + 4096 + (w + 4 * i) * 512 + l * 8);
        }
#pragma unroll
        for (int i = 0; i < 4; ++i) {
            const int rbase = (w + 4 * i) * 16;
            load_lds16(gB + (size_t)(rbase + rr) * 64 + p * 8,
                       d + 8192 + (w + 4 * i) * 512 + l * 8);
        }
    };

    // ---- prologue: stage sub-chunk 0 into buf0; syncthreads drains vmcnt ----
    STAGE(0);
    __syncthreads();

    // per-stripe compacted top-2 (lane cc holds row-slot cc of its q-group)
    unsigned long long s1a = ~0ULL, s2a = ~0ULL, s1b = ~0ULL, s2b = ~0ULL;
    unsigned long long s1c = ~0ULL, s2c = ~0ULL, s1d = ~0ULL, s2d = ~0ULL;

    f32x4 acc[4][8];
#pragma unroll
    for (int tm = 0; tm < 4; ++tm)
#pragma unroll
        for (int tn = 0; tn < 8; ++tn) { f32x4 z = {0.f,0.f,0.f,0.f}; acc[tm][tn] = z; }

    // it = n0*16 + c64*2 + h : 4 stripes x 8 chunks x 2 sub-chunks
#pragma unroll 1
    for (int it = 0; it < 64; ++it) {
        if (it < 63) {
            STAGE(it + 1);                       // into buf[(it+1)&1]
            __builtin_amdgcn_sched_barrier(0);   // keep DMA issue at the top
        }

        const char* bb = (const char*)buf + (it & 1) * 32768;
        f16x8 Ah[4], Al[4], Bf[8];
#pragma unroll
        for (int t = 0; t < 4; ++t) {
            Ah[t] = *(const f16x8*)(bb + rdA[t]);
            Al[t] = *(const f16x8*)(bb + 8192 + rdA[t]);
        }
#pragma unroll
        for (int t = 0; t < 8; ++t)
            Bf[t] = *(const f16x8*)(bb + 16384 + rdB[t]);
#pragma unroll
        for (int tm = 0; tm < 4; ++tm)
#pragma unroll
            for (int tn = 0; tn < 8; ++tn)
                acc[tm][tn] = MFMA16(Ah[tm], Bf[tn], acc[tm][tn]);
#pragma unroll
        for (int tm = 0; tm < 4; ++tm)
#pragma unroll
            for (int tn = 0; tn < 8; ++tn)
                acc[tm][tn] = MFMA16(Al[tm], Bf[tn], acc[tm][tn]);

        // ---- stripe epilogue (overlaps the in-flight prefetch) ----
        if ((it & 15) == 15) {
            const int n0 = it >> 4;
            unsigned long long k1[16], k2[16];
#pragma unroll
            for (int s = 0; s < 16; ++s) { k1[s] = ~0ULL; k2[s] = ~0ULL; }
            float c2v[8];
#pragma unroll
            for (int tn = 0; tn < 8; ++tn)
                c2v[tn] = c2s[n0 * 256 + wn * 128 + tn * 16 + cc];
#pragma unroll
            for (int tm = 0; tm < 4; ++tm)
#pragma unroll
                for (int r = 0; r < 4; ++r) {
                    const int s = tm * 4 + r;
                    float x2v = x2s[wm * 64 + tm * 16 + q * 4 + r];
#pragma unroll
                    for (int tn = 0; tn < 8; ++tn) {
                        unsigned col = nb + n0 * 256 + wn * 128 + tn * 16 + cc;
                        float dd = (x2v - 2.0f * acc[tm][tn][r]) + c2v[tn];
                        unsigned long long key =
                            ((unsigned long long)__float_as_uint(dd) << 12) | col;
                        if (key < k1[s]) { k2[s] = k1[s]; k1[s] = key; }
                        else if (key < k2[s]) { k2[s] = key; }
                    }
                }
            // butterfly top-2 merge across the 16 col-lanes (per slot)
#pragma unroll
            for (int s = 0; s < 16; ++s) {
#pragma unroll
                for (int m = 1; m < 16; m <<= 1) {
                    unsigned long long o1 = __shfl_xor(k1[s], m, 64);
                    unsigned long long o2 = __shfl_xor(k2[s], m, 64);
                    unsigned long long lf = k1[s] > o1 ? k1[s] : o1;
                    unsigned long long ws_ = k2[s] < o2 ? k2[s] : o2;
                    k1[s] = k1[s] < o1 ? k1[s] : o1;
                    k2[s] = lf < ws_ ? lf : ws_;
                }
            }
            // compact: lane cc keeps slot cc (static predicated selects)
            unsigned long long m1 = k1[0], m2 = k2[0];
#pragma unroll
            for (int s = 1; s < 16; ++s) {
                if (cc == s) { m1 = k1[s]; m2 = k2[s]; }
            }
            if (n0 == 0)      { s1a = m1; s2a = m2; }
            else if (n0 == 1) { s1b = m1; s2b = m2; }
            else if (n0 == 2) { s1c = m1; s2c = m2; }
            else              { s1d = m1; s2d = m2; }
            // re-zero acc for next stripe
#pragma unroll
            for (int tm = 0; tm < 4; ++tm)
#pragma unroll
                for (int tn = 0; tn < 8; ++tn) { f32x4 z = {0.f,0.f,0.f,0.f}; acc[tm][tn] = z; }
        }

        __syncthreads();   // drains DMA(it+1) (issued ~a full compute ago) + read/write fence
    }

    // ---- final: merge 2 wn-halves x 4 stripes per row via LDS (aliases buf) ----
    unsigned long long* sc = (unsigned long long*)buf;   // [128 rows][2 wn][4 n0][2] = 16 KiB
    {
        int rloc = (cc >> 2) * 16 + q * 4 + (cc & 3);    // 0..63 bijective
        int r    = wm * 64 + rloc;
        size_t base = (size_t)((r * 2 + wn) * 4) * 2;
        sc[base + 0] = s1a; sc[base + 1] = s2a;
        sc[base + 2] = s1b; sc[base + 3] = s2b;
        sc[base + 4] = s1c; sc[base + 5] = s2c;
        sc[base + 6] = s1d; sc[base + 7] = s2d;
    }
    __syncthreads();
    if (tid < 128) {
        unsigned long long m1 = ~0ULL, m2 = ~0ULL;
#pragma unroll
        for (int j = 0; j < 8; ++j) {                    // 2 wn x 4 stripes
            unsigned long long b1 = sc[(size_t)(tid * 8 + j) * 2 + 0];
            unsigned long long b2 = sc[(size_t)(tid * 8 + j) * 2 + 1];
            unsigned long long lf  = m1 > b1 ? m1 : b1;
            unsigned long long ws_ = m2 < b2 ? m2 : b2;
            m1 = m1 < b1 ? m1 : b1;
            m2 = lf < ws_ ? lf : ws_;
        }
        size_t base = (size_t)(row0 + tid) * 8 + blockIdx.y * 2;
        cand[base + 0] = (unsigned short)(m1 & 0xFFFULL);
        cand[base + 1] = (unsigned short)(m2 & 0xFFFULL);
    }
}

// ================= fallback argmin (round-1 verbatim, proven) ===============
__global__ __launch_bounds__(256) void argmin_fb(
    const float* __restrict__ x, const float* __restrict__ cb,
    const float* __restrict__ x2, const float* __restrict__ c2,
    unsigned long long* __restrict__ keys)
{
    __shared__ __align__(16) float As[32][68];
    __shared__ __align__(16) float Bs[32][68];
    __shared__ float rv[64][16];
    __shared__ int   ri[64][16];

    const int tid  = threadIdx.x;
    const int tx   = tid & 15;
    const int ty   = tid >> 4;
    const int row0 = blockIdx.x * 64;
    const int nb   = blockIdx.y * 1024;

    float x2r[4];
#pragma unroll
    for (int m = 0; m < 4; ++m) x2r[m] = x2[row0 + ty * 4 + m];

    float minv[4]; int mini[4];
#pragma unroll
    for (int m = 0; m < 4; ++m) { minv[m] = 3.4028235e38f; mini[m] = 0; }

    for (int n0 = 0; n0 < 1024; n0 += 64) {
        float acc[4][4];
#pragma unroll
        for (int m = 0; m < 4; ++m)
#pragma unroll
            for (int n = 0; n < 4; ++n) acc[m][n] = 0.f;

        for (int d0 = 0; d0 < D; d0 += 32) {
            __syncthreads();
#pragma unroll
            for (int j = 0; j < 2; ++j) {
                int v   = j * 256 + tid;
                int row = v >> 3;
                int col = (v & 7) * 4;
                float4 av = *(const float4*)(x  + (size_t)(row0 + row) * D + d0 + col);
                As[col + 0][row] = av.x; As[col + 1][row] = av.y;
                As[col + 2][row] = av.z; As[col + 3][row] = av.w;
                float4 bv = *(const float4*)(cb + (size_t)(nb + n0 + row) * D + d0 + col);
                Bs[col + 0][row] = bv.x; Bs[col + 1][row] = bv.y;
                Bs[col + 2][row] = bv.z; Bs[col + 3][row] = bv.w;
            }
            __syncthreads();
#pragma unroll
            for (int kk = 0; kk < 32; ++kk) {
                float4 a4 = *(const float4*)&As[kk][ty * 4];
                float4 b4 = *(const float4*)&Bs[kk][tx * 4];
                float a_[4] = { a4.x, a4.y, a4.z, a4.w };
                float b_[4] = { b4.x, b4.y, b4.z, b4.w };
#pragma unroll
                for (int m = 0; m < 4; ++m)
#pragma unroll
                    for (int n = 0; n < 4; ++n)
                        acc[m][n] = fmaf(a_[m], b_[n], acc[m][n]);
            }
        }
#pragma unroll
        for (int n = 0; n < 4; ++n) {
            int kidx = nb + n0 + tx * 4 + n;
            float c2k = c2[kidx];
#pragma unroll
            for (int m = 0; m < 4; ++m) {
                float wv = x2r[m] - 2.0f * acc[m][n];
                float dd = wv + c2k;
                if (dd < minv[m]) { minv[m] = dd; mini[m] = kidx; }
            }
        }
    }
#pragma unroll
    for (int m = 0; m < 4; ++m) { rv[ty * 4 + m][tx] = minv[m]; ri[ty * 4 + m][tx] = mini[m]; }
    __syncthreads();
    if (tid < 64) {
        float bv = rv[tid][0]; int bi = ri[tid][0];
#pragma unroll
        for (int j = 1; j < 16; ++j) {
            float v = rv[tid][j]; int ii = ri[tid][j];
            if (v < bv || (v == bv && ii < bi)) { bv = v; bi = ii; }
        }
        unsigned long long key =
            ((unsigned long long)__float_as_uint(bv) << 12) | (unsigned long long)bi;
        atomicMin(&keys[row0 + tid], key);
    }
}

// ================= downstream ==============================================

__global__ void count_kernel(const unsigned long long* __restrict__ keys,
                             float* __restrict__ counts, unsigned short* __restrict__ idx16)
{
    int i = blockIdx.x * 256 + threadIdx.x;
    int k = (int)(keys[i] & 0xFFFULL);
    idx16[i] = (unsigned short)k;
    atomicAdd(&counts[k], 1.0f);
}

__global__ __launch_bounds__(256) void ema_cluster_kernel(
    const float* __restrict__ hc, const float* __restrict__ counts,
    const float* __restrict__ countp, float* __restrict__ avgc, float* __restrict__ Nout)
{
    __shared__ float sm[256];
    int i = blockIdx.x * 256 + threadIdx.x;
    const float om = 1.0f - 0.99f;
    float bias = 1.0f - powf(0.99f, countp[0] + 1.0f);
    float a = (hc[i] * 0.99f + om * counts[i]) / bias;
    avgc[i] = a;
    sm[threadIdx.x] = a;
    __syncthreads();
    for (int s = 128; s > 0; s >>= 1) {
        if (threadIdx.x < s) sm[threadIdx.x] += sm[threadIdx.x + s];
        __syncthreads();
    }
    if (threadIdx.x == 0) atomicAdd(Nout, sm[0]);
}

// per-code gather of assigned x rows + EMA + codebook_new (scans compact u16 idx)
__global__ __launch_bounds__(256) void code_update_kernel(
    const float* __restrict__ x, const unsigned short* __restrict__ idx16,
    const float* __restrict__ hdw, const float* __restrict__ avgc,
    const float* __restrict__ Nptr, const float* __restrict__ countp,
    float* __restrict__ cbn)
{
    __shared__ unsigned short rows[2048];
    __shared__ int cnt;
    int k = blockIdx.x, tid = threadIdx.x;
    if (tid == 0) cnt = 0;
    __syncthreads();
    const uint4* ip = (const uint4*)idx16;   // 2048 x (8 u16)
    for (int j = 0; j < 8; ++j) {
        int u = j * 256 + tid;
        uint4 v = ip[u];
        unsigned ww[4] = {v.x, v.y, v.z, v.w};
#pragma unroll
        for (int e = 0; e < 4; ++e) {
            int k0 = (int)(ww[e] & 0xFFFFu), k1 = (int)(ww[e] >> 16);
            if (k0 == k) { int p = atomicAdd(&cnt, 1); if (p < 2048) rows[p] = (unsigned short)(u * 8 + e * 2); }
            if (k1 == k) { int p = atomicAdd(&cnt, 1); if (p < 2048) rows[p] = (unsigned short)(u * 8 + e * 2 + 1); }
        }
    }
    __syncthreads();
    int n = cnt < 2048 ? cnt : 2048;
    float a0 = 0.f, a1 = 0.f;
    for (int p = 0; p < n; ++p) {
        int r = rows[p];
        a0 += x[(size_t)r * D + tid];
        a1 += x[(size_t)r * D + tid + 256];
    }
    const float om = 1.0f - 0.99f;
    float bias = 1.0f - powf(0.99f, countp[0] + 1.0f);
    float Nv = *Nptr;
    float ccv = ((avgc[k] + 1e-5f) / (Nv + 0.04096f)) * Nv;
    size_t b = (size_t)k * D;
    cbn[b + tid]       = ((hdw[b + tid]       * 0.99f + om * a0) / bias) / ccv;
    cbn[b + tid + 256] = ((hdw[b + tid + 256] * 0.99f + om * a1) / bias) / ccv;
}

__global__ __launch_bounds__(256) void gather_kernel(
    const float* __restrict__ x, const unsigned long long* __restrict__ keys,
    const float* __restrict__ cbn, float* __restrict__ outq,
    float* __restrict__ partial)
{
    __shared__ float sm[256];
    int row = blockIdx.x;
    int tid = threadIdx.x;
    int k   = (int)(keys[row] & 0xFFFULL);
    const float* xpp = x   + (size_t)row * D;
    const float* cp  = cbn + (size_t)k   * D;
    float* op = outq + (size_t)row * D;
    float local = 0.f;
#pragma unroll
    for (int j = 0; j < 2; ++j) {
        int d = tid + j * 256;
        float xv = xpp[d];
        float qv = cp[d];
        float quant = xv + (qv - xv);
        op[d] = quant;
        float diff = xv - quant;
        local = fmaf(diff, diff, local);
    }
    sm[tid] = local;
    __syncthreads();
    for (int s = 128; s > 0; s >>= 1) {
        if (tid < s) sm[tid] += sm[tid + s];
        __syncthreads();
    }
    if (tid == 0) {
        partial[row] = sm[0];
        outq[8388609 + row] = (float)k;
    }
}

__global__ __launch_bounds__(256) void finalize_kernel(
    const float* __restrict__ partial, float* __restrict__ out)
{
    __shared__ double sm[256];
    int tid = threadIdx.x;
    double s = 0.0;
#pragma unroll
    for (int j = 0; j < 64; ++j) s += (double)partial[tid + j * 256];
    sm[tid] = s;
    __syncthreads();
    for (int st = 128; st > 0; st >>= 1) {
        if (tid < st) sm[tid] += sm[tid + st];
        __syncthreads();
    }
    if (tid == 0) out[8388608] = (float)(0.5 * sm[0] / 8388608.0);
}

// ================= launcher ================================================

extern "C" void kernel_launch(void* const* d_in, const int* in_sizes, int n_in,
                              void* d_out, int out_size, void* d_ws, size_t ws_size,
                              hipStream_t stream)
{
    const float* x   = (const float*)d_in[0];
    const float* cb  = (const float*)d_in[1];
    const float* hc  = (const float*)d_in[2];
    const float* hdw = (const float*)d_in[3];
    const float* cnt = (const float*)d_in[4];
    float* out = (float*)d_out;

    char* ws = (char*)d_ws;
    float*  c2     = (float*)(ws + OFF_C2);
    float*  x2     = (float*)(ws + OFF_X2);
    float*  counts = (float*)(ws + OFF_CNT);
    float*  avgc   = (float*)(ws + OFF_AVGC);
    float*  Nout   = (float*)(ws + OFF_SCAL + 8);
    unsigned short* idx16 = (unsigned short*)(ws + OFF_IDX16);
    unsigned long long* keys = (unsigned long long*)(ws + OFF_KEYS);
    float*  partial= (float*)(ws + OFF_X2);   // x2 dead after rescore

    hipMemsetAsync(ws + OFF_CNT, 0, (32 << 10) + 16, stream);

    rowsq_all<<<K + BL, 64, 0, stream>>>(x, cb, x2, c2);

    const bool primary = ws_size >= ((size_t)10 << 20);
    float* cbn;
    if (primary) {
        // xh'+xl' streams = 2*8*16384*128 B = 33,554,432 B: exactly d_out's
        // quantized region; gather overwrites at the end. cb' (hi) = 4.19 MB in ws.
        unsigned short* gxp = (unsigned short*)d_out;
        unsigned short* gcp = (unsigned short*)(ws + OFF_CBP);
        unsigned short* cand = (unsigned short*)(ws + OFF_CAND);
        cbn = (float*)(ws + OFF_CBP);   // reuses cb' after argmin

        split_interleave<<<5120, 256, 0, stream>>>(x, cb, gxp, gcp);
        argmin_mfma<<<dim3(BL / 128, 4), 256, 0, stream>>>(gxp, gcp, x2, c2, cand);
        rescore_kernel<<<(BL * 8) / 256, 256, 0, stream>>>(x, cb, x2, c2, cand, keys,
                                                           counts, idx16);
    } else {
        cbn = (float*)(ws + OFF_CBN_FB);
        hipMemsetAsync(ws + OFF_KEYS, 0xFF, BL * 8, stream);
        argmin_fb<<<dim3(BL / 64, 4), 256, 0, stream>>>(x, cb, x2, c2, keys);
        count_kernel<<<BL / 256, 256, 0, stream>>>(keys, counts, idx16);
    }

    ema_cluster_kernel<<<K / 256, 256, 0, stream>>>(hc, counts, cnt, avgc, Nout);
    code_update_kernel<<<K, 256, 0, stream>>>(x, idx16, hdw, avgc, Nout, cnt, cbn);
    gather_kernel<<<BL, 256, 0, stream>>>(x, keys, cbn, out, partial);
    finalize_kernel<<<1, 256, 0, stream>>>(partial, out);
}

// Round 7
// 336.347 us; speedup vs baseline: 1.0112x; 1.0112x over previous
//
#include <hip/hip_runtime.h>
#include <math.h>

#define BL 16384
#define D  512
#define K  4096
#define NCHB 8          // 64-k chunks: 512 k / 64
#define XLOFF 8388608   // halves offset of xl' stream inside d_out region

// ---- ws layout (bytes) ----
#define OFF_C2    0                // 4096 f
#define OFF_X2    (16<<10)         // 16384 f (aliased as loss partials after rescore)
#define OFF_CNT   (80<<10)         // 4096 f
#define OFF_AVGC  (96<<10)         // 4096 f
#define OFF_SCAL  (112<<10)        // N float @+8
#define OFF_IDX16 (116<<10)        // 16384 u16
#define OFF_KEYS  (160<<10)        // 16384 u64
#define OFF_CAND  (288<<10)        // 16384*8 u16
#define OFF_CBP   (576<<10)        // cb' 8*4096*128 B = 4.19 MB; cbn (8 MB) reuses after argmin
#define OFF_CBN_FB (256<<10)       // fallback cbn

typedef _Float16 f16x8 __attribute__((ext_vector_type(8)));
typedef float    f32x4 __attribute__((ext_vector_type(4)));
#define MFMA16(a,b,c) __builtin_amdgcn_mfma_f32_16x16x32_f16(a,b,c,0,0,0)

// ================= bit-exact helpers (feed exact rescore — DO NOT TOUCH) ====

__global__ void rowsq_all(const float* __restrict__ x, const float* __restrict__ cb,
                          float* __restrict__ x2, float* __restrict__ c2)
{
    int b    = blockIdx.x;
    int lane = threadIdx.x;              // 64
    const float* p; float* o; int row;
    if (b < K) { p = cb; o = c2; row = b; }
    else       { p = x;  o = x2; row = b - K; }
    p += (size_t)row * D;
    float s = 0.f;
#pragma unroll
    for (int j = 0; j < D / 64; ++j) {
        float v = p[lane + j * 64];
        s = fmaf(v, v, s);
    }
#pragma unroll
    for (int off = 32; off > 0; off >>= 1)
        s += __shfl_down(s, off, 64);
    if (lane == 0) o[row] = s;
}

// exact rescore, bit-identical arithmetic to round-1 (sequential fmaf k=0..511);
// also emits counts + compact u16 indices.
__global__ __launch_bounds__(256) void rescore_kernel(
    const float* __restrict__ x, const float* __restrict__ cb,
    const float* __restrict__ x2, const float* __restrict__ c2,
    const unsigned short* __restrict__ cand,
    unsigned long long* __restrict__ keys,
    float* __restrict__ counts, unsigned short* __restrict__ idx16)
{
    int t = blockIdx.x * 256 + threadIdx.x;  // 131072
    int row = t >> 3, ci = t & 7;
    int idx = cand[(size_t)row * 8 + ci];
    const float* xp = x  + (size_t)row * D;
    const float* cp = cb + (size_t)idx * D;
    float acc = 0.f;
#pragma unroll 4
    for (int k0 = 0; k0 < D; k0 += 4) {
        float4 xv = *(const float4*)(xp + k0);
        float4 cv = *(const float4*)(cp + k0);
        acc = fmaf(xv.x, cv.x, acc);
        acc = fmaf(xv.y, cv.y, acc);
        acc = fmaf(xv.z, cv.z, acc);
        acc = fmaf(xv.w, cv.w, acc);
    }
    float wv = x2[row] - 2.0f * acc;
    float dd = wv + c2[idx];
    unsigned long long key =
        ((unsigned long long)__float_as_uint(dd) << 12) | (unsigned long long)idx;
#pragma unroll
    for (int m = 1; m < 8; m <<= 1) {
        unsigned long long o = __shfl_xor(key, m, 64);
        key = o < key ? o : key;
    }
    if ((t & 7) == 0) {
        keys[row] = key;
        int kf = (int)(key & 0xFFFULL);
        idx16[row] = (unsigned short)kf;
        atomicAdd(&counts[kf], 1.0f);
    }
}

// ================= primary path ============================================

__device__ __forceinline__ void load_lds16(const unsigned short* g, unsigned short* l) {
    __builtin_amdgcn_global_load_lds(
        (const __attribute__((address_space(1))) unsigned int*)(g),
        (__attribute__((address_space(3))) unsigned int*)(l), 16, 0, 0);
}

// fp32 -> fp16 hi/lo streams. 64-k chunks, 128 B rows, 8 granules x 16 B,
// phys granule p = g ^ (row&7) (g = k-group 0..7, k = 64c + 8g .. +7).
// x: hi stream at xp[0..], lo stream at xp[XLOFF..]. cb: hi only.
__global__ __launch_bounds__(256) void split_interleave(
    const float* __restrict__ x, const float* __restrict__ cb,
    unsigned short* __restrict__ xp, unsigned short* __restrict__ cbp)
{
    int gw   = blockIdx.x * 4 + (threadIdx.x >> 6);  // 0..20479
    int lane = threadIdx.x & 63;
    int rl   = lane >> 3;
    int p    = lane & 7;
    const float* src; int nr, c, r0; bool isX;
    if (gw < 16384) { c = gw >> 11; r0 = (gw & 2047) * 8; src = x;  nr = BL; isX = true; }
    else { int lw = gw - 16384; c = lw >> 9; r0 = (lw & 511) * 8; src = cb; nr = K; isX = false; }
    int r = r0 + rl;
    int g = p ^ rl;                  // r&7 == rl
    const float* sp = src + (size_t)r * D + c * 64 + g * 8;
    float4 f0 = *(const float4*)sp, f1 = *(const float4*)(sp + 4);
    float f[8] = {f0.x,f0.y,f0.z,f0.w,f1.x,f1.y,f1.z,f1.w};
    __align__(16) _Float16 oh[8], ol[8];
#pragma unroll
    for (int i = 0; i < 8; ++i) {
        _Float16 h = (_Float16)f[i];           // RNE
        oh[i] = h;
        ol[i] = (_Float16)(f[i] - (float)h);   // exact residual -> RNE fp16
    }
    size_t off = ((size_t)(c * nr + r) * 8 + p) * 8;   // halves
    if (isX) {
        *(uint4*)(xp + off)         = *(const uint4*)oh;
        *(uint4*)(xp + XLOFF + off) = *(const uint4*)ol;
    } else {
        *(uint4*)(cbp + off) = *(const uint4*)oh;
    }
}

// MFMA approx distance + per-split top-2 — round-4 geometry (4 waves,
// 128 rows x 1024 codes, wave tile 64x128, 0.25 ds_read/MFMA, 2 blocks/CU)
// with the 64-k chunk split into two 32-k sub-chunks (32 KB each) double-
// buffered in 64 KB: per sub-chunk it: issue DMA(it+1) into the other
// buffer, compute it, one __syncthreads at the bottom — the drain targets
// loads issued a full ~2400-cyc compute earlier (exposure ~0).
// CONFLICT FIX vs round-5: 64-B rows conflict when rows share row&1, so
// the granule SLOT is XOR-swizzled with (row>>1)&3 on BOTH sides:
//   read  slot = q  ^ ((row>>1)&3)
//   stage slot jr holds logical granule q' = jr ^ ((row>>1)&3),
//         i.e. source phys granule p = ((h<<2)|q') ^ (row&7)
// -> start banks (cc&1)*16 + slot*4: 8 distinct 16B slots x 8 lanes = the
// same distribution signature round-4 measured at 688K conflicts (~free).
// MFMA operands per lane identical to round-4 -> bit-identical acc.
__global__ __launch_bounds__(256, 2) void argmin_mfma(
    const unsigned short* __restrict__ xp, const unsigned short* __restrict__ cbp,
    const float* __restrict__ x2, const float* __restrict__ c2,
    unsigned short* __restrict__ cand)
{
    __shared__ __align__(16) unsigned short buf[2 * 16384];  // 2 x 32 KiB dbuf
    __shared__ __align__(16) float c2s[1024];                // 4 KiB
    __shared__ float x2s[128];

    // u16 offsets inside one buffer: A-hi 0 (8KB), A-lo 4096 (8KB), B 8192 (16KB)

    const int tid = threadIdx.x;        // 0..255
    const int l   = tid & 63;
    const int w   = tid >> 6;           // 0..3
    const int wm  = w >> 1;             // 0..1  row half
    const int wn  = w & 1;              // 0..1  col half (128 cols each)
    const int q   = l >> 4;             // quad -> k-subgroup (granule)
    const int cc  = l & 15;             // row/col lane
    const int row0 = blockIdx.x * 128;
    const int nb   = blockIdx.y * 1024;

    // stash x2/c2 (keeps loop free of stray VMEM)
    if (tid < 128) x2s[tid] = x2[row0 + tid];
#pragma unroll
    for (int j = 0; j < 4; ++j) c2s[j * 256 + tid] = c2[nb + j * 256 + tid];

    // chunk-invariant LDS BYTE offsets; slot = q ^ ((row>>1)&3), row>>1&3 == cc>>1&3
    const int slot = (q ^ ((cc >> 1) & 3)) * 16;
    int rdA[4], rdB[8];
#pragma unroll
    for (int t = 0; t < 4; ++t)
        rdA[t] = (wm * 64 + t * 16 + cc) * 64 + slot;       // < 8192
#pragma unroll
    for (int t = 0; t < 8; ++t)
        rdB[t] = (wn * 128 + t * 16 + cc) * 64 + slot;      // < 16384

    // stage sub-chunk s (s = n0*16 + c64*2 + h) into buf[s&1].
    // Lane l covers row rr=l>>2 (of 16-row block), slot jr=l&3; the slot
    // holds logical granule q' = jr ^ ((rr>>1)&3); source phys granule
    // p = ((h<<2)|q') ^ (rr&7).  Dest is wave-uniform base + lane*16B.
    auto STAGE = [&](int s) {
        const int n0s = s >> 4, c64 = (s >> 1) & 7, h = s & 1;
        unsigned short* d = buf + (s & 1) * 16384;
        const int jr = l & 3, rr = l >> 2;
        const int qp = jr ^ ((rr >> 1) & 3);
        const int p  = ((h << 2) | qp) ^ (rr & 7);          // row&7 == rr&7 (16-row aligned)
        const unsigned short* gAh = xp + (((size_t)c64 * BL + row0) << 6);
        const unsigned short* gAl = gAh + XLOFF;
        const unsigned short* gB  = cbp + (((size_t)c64 * K + nb + n0s * 256) << 6);
#pragma unroll
        for (int i = 0; i < 2; ++i) {
            const int rbase = (w + 4 * i) * 16;
            load_lds16(gAh + (size_t)(rbase + rr) * 64 + p * 8,
                       d + (w + 4 * i) * 512 + l * 8);
            load_lds16(gAl + (size_t)(rbase + rr) * 64 + p * 8,
                       d + 4096 + (w + 4 * i) * 512 + l * 8);
        }
#pragma unroll
        for (int i = 0; i < 4; ++i) {
            const int rbase = (w + 4 * i) * 16;
            load_lds16(gB + (size_t)(rbase + rr) * 64 + p * 8,
                       d + 8192 + (w + 4 * i) * 512 + l * 8);
        }
    };

    // ---- prologue: stage sub-chunk 0 into buf0; syncthreads drains vmcnt ----
    STAGE(0);
    __syncthreads();

    // per-stripe compacted top-2 (lane cc holds row-slot cc of its q-group)
    unsigned long long s1a = ~0ULL, s2a = ~0ULL, s1b = ~0ULL, s2b = ~0ULL;
    unsigned long long s1c = ~0ULL, s2c = ~0ULL, s1d = ~0ULL, s2d = ~0ULL;

    f32x4 acc[4][8];
#pragma unroll
    for (int tm = 0; tm < 4; ++tm)
#pragma unroll
        for (int tn = 0; tn < 8; ++tn) { f32x4 z = {0.f,0.f,0.f,0.f}; acc[tm][tn] = z; }

    // it = n0*16 + c64*2 + h : 4 stripes x 8 chunks x 2 sub-chunks
#pragma unroll 1
    for (int it = 0; it < 64; ++it) {
        if (it < 63) {
            STAGE(it + 1);                       // into buf[(it+1)&1]
            __builtin_amdgcn_sched_barrier(0);   // keep DMA issue at the top
        }

        const char* bb = (const char*)buf + (it & 1) * 32768;
        f16x8 Ah[4], Al[4], Bf[8];
#pragma unroll
        for (int t = 0; t < 4; ++t) {
            Ah[t] = *(const f16x8*)(bb + rdA[t]);
            Al[t] = *(const f16x8*)(bb + 8192 + rdA[t]);
        }
#pragma unroll
        for (int t = 0; t < 8; ++t)
            Bf[t] = *(const f16x8*)(bb + 16384 + rdB[t]);
#pragma unroll
        for (int tm = 0; tm < 4; ++tm)
#pragma unroll
            for (int tn = 0; tn < 8; ++tn)
                acc[tm][tn] = MFMA16(Ah[tm], Bf[tn], acc[tm][tn]);
#pragma unroll
        for (int tm = 0; tm < 4; ++tm)
#pragma unroll
            for (int tn = 0; tn < 8; ++tn)
                acc[tm][tn] = MFMA16(Al[tm], Bf[tn], acc[tm][tn]);

        // ---- stripe epilogue (overlaps the in-flight prefetch) ----
        if ((it & 15) == 15) {
            const int n0 = it >> 4;
            unsigned long long k1[16], k2[16];
#pragma unroll
            for (int s = 0; s < 16; ++s) { k1[s] = ~0ULL; k2[s] = ~0ULL; }
            float c2v[8];
#pragma unroll
            for (int tn = 0; tn < 8; ++tn)
                c2v[tn] = c2s[n0 * 256 + wn * 128 + tn * 16 + cc];
#pragma unroll
            for (int tm = 0; tm < 4; ++tm)
#pragma unroll
                for (int r = 0; r < 4; ++r) {
                    const int s = tm * 4 + r;
                    float x2v = x2s[wm * 64 + tm * 16 + q * 4 + r];
#pragma unroll
                    for (int tn = 0; tn < 8; ++tn) {
                        unsigned col = nb + n0 * 256 + wn * 128 + tn * 16 + cc;
                        float dd = (x2v - 2.0f * acc[tm][tn][r]) + c2v[tn];
                        unsigned long long key =
                            ((unsigned long long)__float_as_uint(dd) << 12) | col;
                        if (key < k1[s]) { k2[s] = k1[s]; k1[s] = key; }
                        else if (key < k2[s]) { k2[s] = key; }
                    }
                }
            // butterfly top-2 merge across the 16 col-lanes (per slot)
#pragma unroll
            for (int s = 0; s < 16; ++s) {
#pragma unroll
                for (int m = 1; m < 16; m <<= 1) {
                    unsigned long long o1 = __shfl_xor(k1[s], m, 64);
                    unsigned long long o2 = __shfl_xor(k2[s], m, 64);
                    unsigned long long lf = k1[s] > o1 ? k1[s] : o1;
                    unsigned long long ws_ = k2[s] < o2 ? k2[s] : o2;
                    k1[s] = k1[s] < o1 ? k1[s] : o1;
                    k2[s] = lf < ws_ ? lf : ws_;
                }
            }
            // compact: lane cc keeps slot cc (static predicated selects)
            unsigned long long m1 = k1[0], m2 = k2[0];
#pragma unroll
            for (int s = 1; s < 16; ++s) {
                if (cc == s) { m1 = k1[s]; m2 = k2[s]; }
            }
            if (n0 == 0)      { s1a = m1; s2a = m2; }
            else if (n0 == 1) { s1b = m1; s2b = m2; }
            else if (n0 == 2) { s1c = m1; s2c = m2; }
            else              { s1d = m1; s2d = m2; }
            // re-zero acc for next stripe
#pragma unroll
            for (int tm = 0; tm < 4; ++tm)
#pragma unroll
                for (int tn = 0; tn < 8; ++tn) { f32x4 z = {0.f,0.f,0.f,0.f}; acc[tm][tn] = z; }
        }

        __syncthreads();   // drains DMA(it+1) (issued ~a full compute ago) + read/write fence
    }

    // ---- final: merge 2 wn-halves x 4 stripes per row via LDS (aliases buf) ----
    unsigned long long* sc = (unsigned long long*)buf;   // [128 rows][2 wn][4 n0][2] = 16 KiB
    {
        int rloc = (cc >> 2) * 16 + q * 4 + (cc & 3);    // 0..63 bijective
        int r    = wm * 64 + rloc;
        size_t base = (size_t)((r * 2 + wn) * 4) * 2;
        sc[base + 0] = s1a; sc[base + 1] = s2a;
        sc[base + 2] = s1b; sc[base + 3] = s2b;
        sc[base + 4] = s1c; sc[base + 5] = s2c;
        sc[base + 6] = s1d; sc[base + 7] = s2d;
    }
    __syncthreads();
    if (tid < 128) {
        unsigned long long m1 = ~0ULL, m2 = ~0ULL;
#pragma unroll
        for (int j = 0; j < 8; ++j) {                    // 2 wn x 4 stripes
            unsigned long long b1 = sc[(size_t)(tid * 8 + j) * 2 + 0];
            unsigned long long b2 = sc[(size_t)(tid * 8 + j) * 2 + 1];
            unsigned long long lf  = m1 > b1 ? m1 : b1;
            unsigned long long ws_ = m2 < b2 ? m2 : b2;
            m1 = m1 < b1 ? m1 : b1;
            m2 = lf < ws_ ? lf : ws_;
        }
        size_t base = (size_t)(row0 + tid) * 8 + blockIdx.y * 2;
        cand[base + 0] = (unsigned short)(m1 & 0xFFFULL);
        cand[base + 1] = (unsigned short)(m2 & 0xFFFULL);
    }
}

// ================= fallback argmin (round-1 verbatim, proven) ===============
__global__ __launch_bounds__(256) void argmin_fb(
    const float* __restrict__ x, const float* __restrict__ cb,
    const float* __restrict__ x2, const float* __restrict__ c2,
    unsigned long long* __restrict__ keys)
{
    __shared__ __align__(16) float As[32][68];
    __shared__ __align__(16) float Bs[32][68];
    __shared__ float rv[64][16];
    __shared__ int   ri[64][16];

    const int tid  = threadIdx.x;
    const int tx   = tid & 15;
    const int ty   = tid >> 4;
    const int row0 = blockIdx.x * 64;
    const int nb   = blockIdx.y * 1024;

    float x2r[4];
#pragma unroll
    for (int m = 0; m < 4; ++m) x2r[m] = x2[row0 + ty * 4 + m];

    float minv[4]; int mini[4];
#pragma unroll
    for (int m = 0; m < 4; ++m) { minv[m] = 3.4028235e38f; mini[m] = 0; }

    for (int n0 = 0; n0 < 1024; n0 += 64) {
        float acc[4][4];
#pragma unroll
        for (int m = 0; m < 4; ++m)
#pragma unroll
            for (int n = 0; n < 4; ++n) acc[m][n] = 0.f;

        for (int d0 = 0; d0 < D; d0 += 32) {
            __syncthreads();
#pragma unroll
            for (int j = 0; j < 2; ++j) {
                int v   = j * 256 + tid;
                int row = v >> 3;
                int col = (v & 7) * 4;
                float4 av = *(const float4*)(x  + (size_t)(row0 + row) * D + d0 + col);
                As[col + 0][row] = av.x; As[col + 1][row] = av.y;
                As[col + 2][row] = av.z; As[col + 3][row] = av.w;
                float4 bv = *(const float4*)(cb + (size_t)(nb + n0 + row) * D + d0 + col);
                Bs[col + 0][row] = bv.x; Bs[col + 1][row] = bv.y;
                Bs[col + 2][row] = bv.z; Bs[col + 3][row] = bv.w;
            }
            __syncthreads();
#pragma unroll
            for (int kk = 0; kk < 32; ++kk) {
                float4 a4 = *(const float4*)&As[kk][ty * 4];
                float4 b4 = *(const float4*)&Bs[kk][tx * 4];
                float a_[4] = { a4.x, a4.y, a4.z, a4.w };
                float b_[4] = { b4.x, b4.y, b4.z, b4.w };
#pragma unroll
                for (int m = 0; m < 4; ++m)
#pragma unroll
                    for (int n = 0; n < 4; ++n)
                        acc[m][n] = fmaf(a_[m], b_[n], acc[m][n]);
            }
        }
#pragma unroll
        for (int n = 0; n < 4; ++n) {
            int kidx = nb + n0 + tx * 4 + n;
            float c2k = c2[kidx];
#pragma unroll
            for (int m = 0; m < 4; ++m) {
                float wv = x2r[m] - 2.0f * acc[m][n];
                float dd = wv + c2k;
                if (dd < minv[m]) { minv[m] = dd; mini[m] = kidx; }
            }
        }
    }
#pragma unroll
    for (int m = 0; m < 4; ++m) { rv[ty * 4 + m][tx] = minv[m]; ri[ty * 4 + m][tx] = mini[m]; }
    __syncthreads();
    if (tid < 64) {
        float bv = rv[tid][0]; int bi = ri[tid][0];
#pragma unroll
        for (int j = 1; j < 16; ++j) {
            float v = rv[tid][j]; int ii = ri[tid][j];
            if (v < bv || (v == bv && ii < bi)) { bv = v; bi = ii; }
        }
        unsigned long long key =
            ((unsigned long long)__float_as_uint(bv) << 12) | (unsigned long long)bi;
        atomicMin(&keys[row0 + tid], key);
    }
}

// ================= downstream ==============================================

__global__ void count_kernel(const unsigned long long* __restrict__ keys,
                             float* __restrict__ counts, unsigned short* __restrict__ idx16)
{
    int i = blockIdx.x * 256 + threadIdx.x;
    int k = (int)(keys[i] & 0xFFFULL);
    idx16[i] = (unsigned short)k;
    atomicAdd(&counts[k], 1.0f);
}

__global__ __launch_bounds__(256) void ema_cluster_kernel(
    const float* __restrict__ hc, const float* __restrict__ counts,
    const float* __restrict__ countp, float* __restrict__ avgc, float* __restrict__ Nout)
{
    __shared__ float sm[256];
    int i = blockIdx.x * 256 + threadIdx.x;
    const float om = 1.0f - 0.99f;
    float bias = 1.0f - powf(0.99f, countp[0] + 1.0f);
    float a = (hc[i] * 0.99f + om * counts[i]) / bias;
    avgc[i] = a;
    sm[threadIdx.x] = a;
    __syncthreads();
    for (int s = 128; s > 0; s >>= 1) {
        if (threadIdx.x < s) sm[threadIdx.x] += sm[threadIdx.x + s];
        __syncthreads();
    }
    if (threadIdx.x == 0) atomicAdd(Nout, sm[0]);
}

// per-code gather of assigned x rows + EMA + codebook_new (scans compact u16 idx)
__global__ __launch_bounds__(256) void code_update_kernel(
    const float* __restrict__ x, const unsigned short* __restrict__ idx16,
    const float* __restrict__ hdw, const float* __restrict__ avgc,
    const float* __restrict__ Nptr, const float* __restrict__ countp,
    float* __restrict__ cbn)
{
    __shared__ unsigned short rows[2048];
    __shared__ int cnt;
    int k = blockIdx.x, tid = threadIdx.x;
    if (tid == 0) cnt = 0;
    __syncthreads();
    const uint4* ip = (const uint4*)idx16;   // 2048 x (8 u16)
    for (int j = 0; j < 8; ++j) {
        int u = j * 256 + tid;
        uint4 v = ip[u];
        unsigned ww[4] = {v.x, v.y, v.z, v.w};
#pragma unroll
        for (int e = 0; e < 4; ++e) {
            int k0 = (int)(ww[e] & 0xFFFFu), k1 = (int)(ww[e] >> 16);
            if (k0 == k) { int p = atomicAdd(&cnt, 1); if (p < 2048) rows[p] = (unsigned short)(u * 8 + e * 2); }
            if (k1 == k) { int p = atomicAdd(&cnt, 1); if (p < 2048) rows[p] = (unsigned short)(u * 8 + e * 2 + 1); }
        }
    }
    __syncthreads();
    int n = cnt < 2048 ? cnt : 2048;
    float a0 = 0.f, a1 = 0.f;
    for (int p = 0; p < n; ++p) {
        int r = rows[p];
        a0 += x[(size_t)r * D + tid];
        a1 += x[(size_t)r * D + tid + 256];
    }
    const float om = 1.0f - 0.99f;
    float bias = 1.0f - powf(0.99f, countp[0] + 1.0f);
    float Nv = *Nptr;
    float ccv = ((avgc[k] + 1e-5f) / (Nv + 0.04096f)) * Nv;
    size_t b = (size_t)k * D;
    cbn[b + tid]       = ((hdw[b + tid]       * 0.99f + om * a0) / bias) / ccv;
    cbn[b + tid + 256] = ((hdw[b + tid + 256] * 0.99f + om * a1) / bias) / ccv;
}

__global__ __launch_bounds__(256) void gather_kernel(
    const float* __restrict__ x, const unsigned long long* __restrict__ keys,
    const float* __restrict__ cbn, float* __restrict__ outq,
    float* __restrict__ partial)
{
    __shared__ float sm[256];
    int row = blockIdx.x;
    int tid = threadIdx.x;
    int k   = (int)(keys[row] & 0xFFFULL);
    const float* xpp = x   + (size_t)row * D;
    const float* cp  = cbn + (size_t)k   * D;
    float* op = outq + (size_t)row * D;
    float local = 0.f;
#pragma unroll
    for (int j = 0; j < 2; ++j) {
        int d = tid + j * 256;
        float xv = xpp[d];
        float qv = cp[d];
        float quant = xv + (qv - xv);
        op[d] = quant;
        float diff = xv - quant;
        local = fmaf(diff, diff, local);
    }
    sm[tid] = local;
    __syncthreads();
    for (int s = 128; s > 0; s >>= 1) {
        if (tid < s) sm[tid] += sm[tid + s];
        __syncthreads();
    }
    if (tid == 0) {
        partial[row] = sm[0];
        outq[8388609 + row] = (float)k;
    }
}

__global__ __launch_bounds__(256) void finalize_kernel(
    const float* __restrict__ partial, float* __restrict__ out)
{
    __shared__ double sm[256];
    int tid = threadIdx.x;
    double s = 0.0;
#pragma unroll
    for (int j = 0; j < 64; ++j) s += (double)partial[tid + j * 256];
    sm[tid] = s;
    __syncthreads();
    for (int st = 128; st > 0; st >>= 1) {
        if (tid < st) sm[tid] += sm[tid + st];
        __syncthreads();
    }
    if (tid == 0) out[8388608] = (float)(0.5 * sm[0] / 8388608.0);
}

// ================= launcher ================================================

extern "C" void kernel_launch(void* const* d_in, const int* in_sizes, int n_in,
                              void* d_out, int out_size, void* d_ws, size_t ws_size,
                              hipStream_t stream)
{
    const float* x   = (const float*)d_in[0];
    const float* cb  = (const float*)d_in[1];
    const float* hc  = (const float*)d_in[2];
    const float* hdw = (const float*)d_in[3];
    const float* cnt = (const float*)d_in[4];
    float* out = (float*)d_out;

    char* ws = (char*)d_ws;
    float*  c2     = (float*)(ws + OFF_C2);
    float*  x2     = (float*)(ws + OFF_X2);
    float*  counts = (float*)(ws + OFF_CNT);
    float*  avgc   = (float*)(ws + OFF_AVGC);
    float*  Nout   = (float*)(ws + OFF_SCAL + 8);
    unsigned short* idx16 = (unsigned short*)(ws + OFF_IDX16);
    unsigned long long* keys = (unsigned long long*)(ws + OFF_KEYS);
    float*  partial= (float*)(ws + OFF_X2);   // x2 dead after rescore

    hipMemsetAsync(ws + OFF_CNT, 0, (32 << 10) + 16, stream);

    rowsq_all<<<K + BL, 64, 0, stream>>>(x, cb, x2, c2);

    const bool primary = ws_size >= ((size_t)10 << 20);
    float* cbn;
    if (primary) {
        // xh'+xl' streams = 2*8*16384*128 B = 33,554,432 B: exactly d_out's
        // quantized region; gather overwrites at the end. cb' (hi) = 4.19 MB in ws.
        unsigned short* gxp = (unsigned short*)d_out;
        unsigned short* gcp = (unsigned short*)(ws + OFF_CBP);
        unsigned short* cand = (unsigned short*)(ws + OFF_CAND);
        cbn = (float*)(ws + OFF_CBP);   // reuses cb' after argmin

        split_interleave<<<5120, 256, 0, stream>>>(x, cb, gxp, gcp);
        argmin_mfma<<<dim3(BL / 128, 4), 256, 0, stream>>>(gxp, gcp, x2, c2, cand);
        rescore_kernel<<<(BL * 8) / 256, 256, 0, stream>>>(x, cb, x2, c2, cand, keys,
                                                           counts, idx16);
    } else {
        cbn = (float*)(ws + OFF_CBN_FB);
        hipMemsetAsync(ws + OFF_KEYS, 0xFF, BL * 8, stream);
        argmin_fb<<<dim3(BL / 64, 4), 256, 0, stream>>>(x, cb, x2, c2, keys);
        count_kernel<<<BL / 256, 256, 0, stream>>>(keys, counts, idx16);
    }

    ema_cluster_kernel<<<K / 256, 256, 0, stream>>>(hc, counts, cnt, avgc, Nout);
    code_update_kernel<<<K, 256, 0, stream>>>(x, idx16, hdw, avgc, Nout, cnt, cbn);
    gather_kernel<<<BL, 256, 0, stream>>>(x, keys, cbn, out, partial);
    finalize_kernel<<<1, 256, 0, stream>>>(partial, out);
}

// Round 8
// 315.048 us; speedup vs baseline: 1.0795x; 1.0676x over previous
//
#include <hip/hip_runtime.h>
#include <math.h>

#define BL 16384
#define D  512
#define K  4096
#define NCHB 8          // 64-k chunks: 512 k / 64
#define XLOFF 8388608   // halves offset of xl' stream inside d_out region

// ---- ws layout (bytes) ----
#define OFF_C2    0                // 4096 f
#define OFF_X2    (16<<10)         // 16384 f (aliased as loss partials after rescore)
#define OFF_CNT   (80<<10)         // 4096 f
#define OFF_AVGC  (96<<10)         // 4096 f (unused in primary now)
#define OFF_SCAL  (112<<10)        // scalars: Shc @+16
#define OFF_IDX16 (116<<10)        // 16384 u16
#define OFF_KEYS  (160<<10)        // 16384 u64
#define OFF_CAND  (288<<10)        // 16384*8 u16
#define OFF_CBP   (576<<10)        // cb' 8*4096*128 B = 4.19 MB; cbn (8 MB) reuses after argmin
#define OFF_CBN_FB (256<<10)       // fallback cbn

typedef _Float16 f16x8 __attribute__((ext_vector_type(8)));
typedef float    f32x4 __attribute__((ext_vector_type(4)));
#define MFMA16(a,b,c) __builtin_amdgcn_mfma_f32_16x16x32_f16(a,b,c,0,0,0)

// ================= bit-exact helpers (feed exact rescore — DO NOT TOUCH) ====

// b < K:      c2 row (bit-identical to original rowsq — feeds exact rescore)
// b == K:     S_hc = sum(hidden_cluster)  (order-insensitive, tolerance-safe)
// b > K:      x2 row (FALLBACK PATH ONLY; primary fuses x2 into split_interleave)
__global__ void rowsq_all(const float* __restrict__ x, const float* __restrict__ cb,
                          const float* __restrict__ hc,
                          float* __restrict__ x2, float* __restrict__ c2,
                          float* __restrict__ Shc)
{
    int b    = blockIdx.x;
    int lane = threadIdx.x;              // 64
    if (b == K) {
        float s = 0.f;
#pragma unroll
        for (int j = 0; j < K / 64; ++j) s += hc[lane + j * 64];
#pragma unroll
        for (int off = 32; off > 0; off >>= 1)
            s += __shfl_down(s, off, 64);
        if (lane == 0) Shc[0] = s;
        return;
    }
    const float* p; float* o; int row;
    if (b < K) { p = cb; o = c2; row = b; }
    else       { p = x;  o = x2; row = b - K - 1; }
    p += (size_t)row * D;
    float s = 0.f;
#pragma unroll
    for (int j = 0; j < D / 64; ++j) {
        float v = p[lane + j * 64];
        s = fmaf(v, v, s);
    }
#pragma unroll
    for (int off = 32; off > 0; off >>= 1)
        s += __shfl_down(s, off, 64);
    if (lane == 0) o[row] = s;
}

// exact rescore, bit-identical arithmetic to round-1 (sequential fmaf k=0..511);
// also emits counts + compact u16 indices.
__global__ __launch_bounds__(256) void rescore_kernel(
    const float* __restrict__ x, const float* __restrict__ cb,
    const float* __restrict__ x2, const float* __restrict__ c2,
    const unsigned short* __restrict__ cand,
    unsigned long long* __restrict__ keys,
    float* __restrict__ counts, unsigned short* __restrict__ idx16)
{
    int t = blockIdx.x * 256 + threadIdx.x;  // 131072
    int row = t >> 3, ci = t & 7;
    int idx = cand[(size_t)row * 8 + ci];
    const float* xp = x  + (size_t)row * D;
    const float* cp = cb + (size_t)idx * D;
    float acc = 0.f;
#pragma unroll 4
    for (int k0 = 0; k0 < D; k0 += 4) {
        float4 xv = *(const float4*)(xp + k0);
        float4 cv = *(const float4*)(cp + k0);
        acc = fmaf(xv.x, cv.x, acc);
        acc = fmaf(xv.y, cv.y, acc);
        acc = fmaf(xv.z, cv.z, acc);
        acc = fmaf(xv.w, cv.w, acc);
    }
    float wv = x2[row] - 2.0f * acc;
    float dd = wv + c2[idx];
    unsigned long long key =
        ((unsigned long long)__float_as_uint(dd) << 12) | (unsigned long long)idx;
#pragma unroll
    for (int m = 1; m < 8; m <<= 1) {
        unsigned long long o = __shfl_xor(key, m, 64);
        key = o < key ? o : key;
    }
    if ((t & 7) == 0) {
        keys[row] = key;
        int kf = (int)(key & 0xFFFULL);
        idx16[row] = (unsigned short)kf;
        atomicAdd(&counts[kf], 1.0f);
    }
}

// ================= primary path ============================================

__device__ __forceinline__ void load_lds16(const unsigned short* g, unsigned short* l) {
    __builtin_amdgcn_global_load_lds(
        (const __attribute__((address_space(1))) unsigned int*)(g),
        (__attribute__((address_space(3))) unsigned int*)(l), 16, 0, 0);
}

// fp32 -> fp16 hi/lo streams + fused x2 (squared-row-sum) for the x stream.
// 64-k chunks, 128 B rows, 8 granules x 16 B, phys granule p = g ^ (row&7).
// x: hi stream at xp[0..], lo stream at xp[XLOFF..]. cb: hi only.
// x2 note: accumulated via 8 atomicAdds/row (one per 64-col chunk). x2 only
// appears as a per-row CONSTANT in candidate comparisons (argmin epilogue,
// rescore dd) -> any summation-order change is selection-invariant. c2 stays
// in rowsq (bit-identical) because it varies across candidates.
__global__ __launch_bounds__(256) void split_interleave(
    const float* __restrict__ x, const float* __restrict__ cb,
    unsigned short* __restrict__ xp, unsigned short* __restrict__ cbp,
    float* __restrict__ x2)
{
    int gw   = blockIdx.x * 4 + (threadIdx.x >> 6);  // 0..20479
    int lane = threadIdx.x & 63;
    int rl   = lane >> 3;
    int p    = lane & 7;
    const float* src; int nr, c, r0; bool isX;
    if (gw < 16384) { c = gw >> 11; r0 = (gw & 2047) * 8; src = x;  nr = BL; isX = true; }
    else { int lw = gw - 16384; c = lw >> 9; r0 = (lw & 511) * 8; src = cb; nr = K; isX = false; }
    int r = r0 + rl;
    int g = p ^ rl;                  // r&7 == rl
    const float* sp = src + (size_t)r * D + c * 64 + g * 8;
    float4 f0 = *(const float4*)sp, f1 = *(const float4*)(sp + 4);
    float f[8] = {f0.x,f0.y,f0.z,f0.w,f1.x,f1.y,f1.z,f1.w};
    __align__(16) _Float16 oh[8], ol[8];
#pragma unroll
    for (int i = 0; i < 8; ++i) {
        _Float16 h = (_Float16)f[i];           // RNE
        oh[i] = h;
        ol[i] = (_Float16)(f[i] - (float)h);   // exact residual -> RNE fp16
    }
    size_t off = ((size_t)(c * nr + r) * 8 + p) * 8;   // halves
    if (isX) {
        *(uint4*)(xp + off)         = *(const uint4*)oh;
        *(uint4*)(xp + XLOFF + off) = *(const uint4*)ol;
        float s = 0.f;
#pragma unroll
        for (int i = 0; i < 8; ++i) s = fmaf(f[i], f[i], s);
        s += __shfl_xor(s, 1, 64);
        s += __shfl_xor(s, 2, 64);
        s += __shfl_xor(s, 4, 64);             // reduce over the 8 lanes of row r
        if (p == 0) atomicAdd(&x2[r], s);
    } else {
        *(uint4*)(cbp + off) = *(const uint4*)oh;
    }
}

// MFMA approx distance + per-split top-2.  PROVEN round-4 structure (best
// measured: 142 us, MfmaUtil 43%): 4 waves, single-buffered LDS, serial
// sync-stage-sync per 64-k chunk, 2 blocks/CU (register-capped: 112 VGPR +
// 128 AGPR acc). Wave tile 64x128 (tm=4, tn=8): 32 ds_read_b128 per 128
// MFMA. Dbuf variants measured WORSE twice (r2: 179, r7: 191) -- cross-block
// slippage already covers the drain; do not re-add.
__global__ __launch_bounds__(256, 2) void argmin_mfma(
    const unsigned short* __restrict__ xp, const unsigned short* __restrict__ cbp,
    const float* __restrict__ x2, const float* __restrict__ c2,
    unsigned short* __restrict__ cand)
{
    __shared__ __align__(16) unsigned short sAh[128 * 64];   // 16 KiB
    __shared__ __align__(16) unsigned short sAl[128 * 64];   // 16 KiB
    __shared__ __align__(16) unsigned short sB [256 * 64];   // 32 KiB
    __shared__ __align__(16) float c2s[1024];                // 4 KiB
    __shared__ float x2s[128];

    const int tid = threadIdx.x;        // 0..255
    const int l   = tid & 63;
    const int w   = tid >> 6;           // 0..3
    const int wm  = w >> 1;             // 0..1  row half
    const int wn  = w & 1;              // 0..1  col half (128 cols each)
    const int q   = l >> 4;             // quad -> k-subgroup
    const int cc  = l & 15;             // row/col lane
    const int row0 = blockIdx.x * 128;
    const int nb   = blockIdx.y * 1024;

    // stash x2/c2 (keeps epilogue free of global loads)
    if (tid < 128) x2s[tid] = x2[row0 + tid];
#pragma unroll
    for (int j = 0; j < 4; ++j) c2s[j * 256 + tid] = c2[nb + j * 256 + tid];

    // chunk-invariant LDS byte offsets for kh=0 (g=q); kh=1 -> ^64 (g=q+4)
    int rdA[4], rdB[8];
#pragma unroll
    for (int t = 0; t < 4; ++t) {
        int ra = wm * 64 + t * 16 + cc;          // 0..127
        rdA[t] = ra * 128 + ((q ^ (ra & 7)) * 16);
    }
#pragma unroll
    for (int t = 0; t < 8; ++t) {
        int rb = wn * 128 + t * 16 + cc;         // 0..255
        rdB[t] = rb * 128 + ((q ^ (rb & 7)) * 16);
    }

    // per-stripe compacted top-2 (lane cc holds row-slot cc of its q-group)
    unsigned long long s1a = ~0ULL, s2a = ~0ULL, s1b = ~0ULL, s2b = ~0ULL;
    unsigned long long s1c = ~0ULL, s2c = ~0ULL, s1d = ~0ULL, s2d = ~0ULL;

#pragma unroll 1
    for (int n0 = 0; n0 < 4; ++n0) {
        f32x4 acc[4][8];
#pragma unroll
        for (int tm = 0; tm < 4; ++tm)
#pragma unroll
            for (int tn = 0; tn < 8; ++tn) { f32x4 z = {0.f,0.f,0.f,0.f}; acc[tm][tn] = z; }

#pragma unroll 1
        for (int c = 0; c < NCHB; ++c) {
            __syncthreads();   // prior chunk's readers done
            {
                size_t abase = ((size_t)c * BL + row0) * 64;
                size_t bbase = ((size_t)(c * K + nb + n0 * 256)) * 64;
#pragma unroll
                for (int i = 0; i < 4; ++i) {
                    load_lds16(xp + abase + i * 2048 + tid * 8, &sAh[i * 2048 + tid * 8]);
                    load_lds16(xp + XLOFF + abase + i * 2048 + tid * 8, &sAl[i * 2048 + tid * 8]);
                }
#pragma unroll
                for (int i = 0; i < 8; ++i)
                    load_lds16(cbp + bbase + i * 2048 + tid * 8, &sB[i * 2048 + tid * 8]);
            }
            __syncthreads();   // DMA drained (syncthreads waits vmcnt)
#pragma unroll
            for (int kh = 0; kh < 2; ++kh) {
                const int xo = kh * 64;
                f16x8 Ah[4], Al[4], Bf[8];
#pragma unroll
                for (int t = 0; t < 4; ++t) {
                    Ah[t] = *(const f16x8*)((const char*)sAh + (rdA[t] ^ xo));
                    Al[t] = *(const f16x8*)((const char*)sAl + (rdA[t] ^ xo));
                }
#pragma unroll
                for (int t = 0; t < 8; ++t)
                    Bf[t] = *(const f16x8*)((const char*)sB + (rdB[t] ^ xo));
#pragma unroll
                for (int tm = 0; tm < 4; ++tm)
#pragma unroll
                    for (int tn = 0; tn < 8; ++tn)
                        acc[tm][tn] = MFMA16(Ah[tm], Bf[tn], acc[tm][tn]);
#pragma unroll
                for (int tm = 0; tm < 4; ++tm)
#pragma unroll
                    for (int tn = 0; tn < 8; ++tn)
                        acc[tm][tn] = MFMA16(Al[tm], Bf[tn], acc[tm][tn]);
            }
        }

        // ---- stripe epilogue: dd + top-2 (C layout: col=lane&15, row=q*4+r) ----
        {
            unsigned long long k1[16], k2[16];
#pragma unroll
            for (int s = 0; s < 16; ++s) { k1[s] = ~0ULL; k2[s] = ~0ULL; }
            float c2v[8];
#pragma unroll
            for (int tn = 0; tn < 8; ++tn)
                c2v[tn] = c2s[n0 * 256 + wn * 128 + tn * 16 + cc];
#pragma unroll
            for (int tm = 0; tm < 4; ++tm)
#pragma unroll
                for (int r = 0; r < 4; ++r) {
                    const int s = tm * 4 + r;
                    float x2v = x2s[wm * 64 + tm * 16 + q * 4 + r];
#pragma unroll
                    for (int tn = 0; tn < 8; ++tn) {
                        unsigned col = nb + n0 * 256 + wn * 128 + tn * 16 + cc;
                        float dd = (x2v - 2.0f * acc[tm][tn][r]) + c2v[tn];
                        unsigned long long key =
                            ((unsigned long long)__float_as_uint(dd) << 12) | col;
                        if (key < k1[s]) { k2[s] = k1[s]; k1[s] = key; }
                        else if (key < k2[s]) { k2[s] = key; }
                    }
                }

            // butterfly top-2 merge across the 16 col-lanes (per slot)
#pragma unroll
            for (int s = 0; s < 16; ++s) {
#pragma unroll
                for (int m = 1; m < 16; m <<= 1) {
                    unsigned long long o1 = __shfl_xor(k1[s], m, 64);
                    unsigned long long o2 = __shfl_xor(k2[s], m, 64);
                    unsigned long long lf = k1[s] > o1 ? k1[s] : o1;
                    unsigned long long ws_ = k2[s] < o2 ? k2[s] : o2;
                    k1[s] = k1[s] < o1 ? k1[s] : o1;
                    k2[s] = lf < ws_ ? lf : ws_;
                }
            }
            // compact: lane cc keeps slot cc (static predicated selects)
            unsigned long long m1 = k1[0], m2 = k2[0];
#pragma unroll
            for (int s = 1; s < 16; ++s) {
                if (cc == s) { m1 = k1[s]; m2 = k2[s]; }
            }
            if (n0 == 0)      { s1a = m1; s2a = m2; }
            else if (n0 == 1) { s1b = m1; s2b = m2; }
            else if (n0 == 2) { s1c = m1; s2c = m2; }
            else              { s1d = m1; s2d = m2; }
        }
    }

    // ---- final: merge 2 wn-halves x 4 stripes per row via LDS (aliases sAh) ----
    __syncthreads();
    unsigned long long* sc = (unsigned long long*)sAh;   // [128 rows][2 wn][4 n0][2] = 16 KiB
    {
        int rloc = (cc >> 2) * 16 + q * 4 + (cc & 3);    // 0..63 bijective
        int r    = wm * 64 + rloc;
        size_t base = (size_t)((r * 2 + wn) * 4) * 2;
        sc[base + 0] = s1a; sc[base + 1] = s2a;
        sc[base + 2] = s1b; sc[base + 3] = s2b;
        sc[base + 4] = s1c; sc[base + 5] = s2c;
        sc[base + 6] = s1d; sc[base + 7] = s2d;
    }
    __syncthreads();
    if (tid < 128) {
        unsigned long long m1 = ~0ULL, m2 = ~0ULL;
#pragma unroll
        for (int j = 0; j < 8; ++j) {                    // 2 wn x 4 stripes
            unsigned long long b1 = sc[(size_t)(tid * 8 + j) * 2 + 0];
            unsigned long long b2 = sc[(size_t)(tid * 8 + j) * 2 + 1];
            unsigned long long lf  = m1 > b1 ? m1 : b1;
            unsigned long long ws_ = m2 < b2 ? m2 : b2;
            m1 = m1 < b1 ? m1 : b1;
            m2 = lf < ws_ ? lf : ws_;
        }
        size_t base = (size_t)(row0 + tid) * 8 + blockIdx.y * 2;
        cand[base + 0] = (unsigned short)(m1 & 0xFFFULL);
        cand[base + 1] = (unsigned short)(m2 & 0xFFFULL);
    }
}

// ================= fallback argmin (round-1 verbatim, proven) ===============
__global__ __launch_bounds__(256) void argmin_fb(
    const float* __restrict__ x, const float* __restrict__ cb,
    const float* __restrict__ x2, const float* __restrict__ c2,
    unsigned long long* __restrict__ keys)
{
    __shared__ __align__(16) float As[32][68];
    __shared__ __align__(16) float Bs[32][68];
    __shared__ float rv[64][16];
    __shared__ int   ri[64][16];

    const int tid  = threadIdx.x;
    const int tx   = tid & 15;
    const int ty   = tid >> 4;
    const int row0 = blockIdx.x * 64;
    const int nb   = blockIdx.y * 1024;

    float x2r[4];
#pragma unroll
    for (int m = 0; m < 4; ++m) x2r[m] = x2[row0 + ty * 4 + m];

    float minv[4]; int mini[4];
#pragma unroll
    for (int m = 0; m < 4; ++m) { minv[m] = 3.4028235e38f; mini[m] = 0; }

    for (int n0 = 0; n0 < 1024; n0 += 64) {
        float acc[4][4];
#pragma unroll
        for (int m = 0; m < 4; ++m)
#pragma unroll
            for (int n = 0; n < 4; ++n) acc[m][n] = 0.f;

        for (int d0 = 0; d0 < D; d0 += 32) {
            __syncthreads();
#pragma unroll
            for (int j = 0; j < 2; ++j) {
                int v   = j * 256 + tid;
                int row = v >> 3;
                int col = (v & 7) * 4;
                float4 av = *(const float4*)(x  + (size_t)(row0 + row) * D + d0 + col);
                As[col + 0][row] = av.x; As[col + 1][row] = av.y;
                As[col + 2][row] = av.z; As[col + 3][row] = av.w;
                float4 bv = *(const float4*)(cb + (size_t)(nb + n0 + row) * D + d0 + col);
                Bs[col + 0][row] = bv.x; Bs[col + 1][row] = bv.y;
                Bs[col + 2][row] = bv.z; Bs[col + 3][row] = bv.w;
            }
            __syncthreads();
#pragma unroll
            for (int kk = 0; kk < 32; ++kk) {
                float4 a4 = *(const float4*)&As[kk][ty * 4];
                float4 b4 = *(const float4*)&Bs[kk][tx * 4];
                float a_[4] = { a4.x, a4.y, a4.z, a4.w };
                float b_[4] = { b4.x, b4.y, b4.z, b4.w };
#pragma unroll
                for (int m = 0; m < 4; ++m)
#pragma unroll
                    for (int n = 0; n < 4; ++n)
                        acc[m][n] = fmaf(a_[m], b_[n], acc[m][n]);
            }
        }
#pragma unroll
        for (int n = 0; n < 4; ++n) {
            int kidx = nb + n0 + tx * 4 + n;
            float c2k = c2[kidx];
#pragma unroll
            for (int m = 0; m < 4; ++m) {
                float wv = x2r[m] - 2.0f * acc[m][n];
                float dd = wv + c2k;
                if (dd < minv[m]) { minv[m] = dd; mini[m] = kidx; }
            }
        }
    }
#pragma unroll
    for (int m = 0; m < 4; ++m) { rv[ty * 4 + m][tx] = minv[m]; ri[ty * 4 + m][tx] = mini[m]; }
    __syncthreads();
    if (tid < 64) {
        float bv = rv[tid][0]; int bi = ri[tid][0];
#pragma unroll
        for (int j = 1; j < 16; ++j) {
            float v = rv[tid][j]; int ii = ri[tid][j];
            if (v < bv || (v == bv && ii < bi)) { bv = v; bi = ii; }
        }
        unsigned long long key =
            ((unsigned long long)__float_as_uint(bv) << 12) | (unsigned long long)bi;
        atomicMin(&keys[row0 + tid], key);
    }
}

// ================= downstream ==============================================

__global__ void count_kernel(const unsigned long long* __restrict__ keys,
                             float* __restrict__ counts, unsigned short* __restrict__ idx16)
{
    int i = blockIdx.x * 256 + threadIdx.x;
    int k = (int)(keys[i] & 0xFFFULL);
    idx16[i] = (unsigned short)k;
    atomicAdd(&counts[k], 1.0f);
}

// per-code gather of assigned x rows + EMA + codebook_new (scans compact u16 idx).
// avgc/N computed in-kernel: N = sum(avgc) = (0.99*sum(hc) + 0.01*sum(counts))/bias
// with sum(counts) == 16384 exactly (every row assigned once); S_hc from rowsq.
// Replaces the separate ema_cluster kernel (order diff ~1e-7, tolerance-safe).
__global__ __launch_bounds__(256) void code_update_kernel(
    const float* __restrict__ x, const unsigned short* __restrict__ idx16,
    const float* __restrict__ hdw, const float* __restrict__ hc,
    const float* __restrict__ counts, const float* __restrict__ Shc,
    const float* __restrict__ countp, float* __restrict__ cbn)
{
    __shared__ unsigned short rows[2048];
    __shared__ int cnt;
    int k = blockIdx.x, tid = threadIdx.x;
    if (tid == 0) cnt = 0;
    __syncthreads();
    const uint4* ip = (const uint4*)idx16;   // 2048 x (8 u16)
    for (int j = 0; j < 8; ++j) {
        int u = j * 256 + tid;
        uint4 v = ip[u];
        unsigned ww[4] = {v.x, v.y, v.z, v.w};
#pragma unroll
        for (int e = 0; e < 4; ++e) {
            int k0 = (int)(ww[e] & 0xFFFFu), k1 = (int)(ww[e] >> 16);
            if (k0 == k) { int p = atomicAdd(&cnt, 1); if (p < 2048) rows[p] = (unsigned short)(u * 8 + e * 2); }
            if (k1 == k) { int p = atomicAdd(&cnt, 1); if (p < 2048) rows[p] = (unsigned short)(u * 8 + e * 2 + 1); }
        }
    }
    __syncthreads();
    int n = cnt < 2048 ? cnt : 2048;
    float a0 = 0.f, a1 = 0.f;
    for (int p = 0; p < n; ++p) {
        int r = rows[p];
        a0 += x[(size_t)r * D + tid];
        a1 += x[(size_t)r * D + tid + 256];
    }
    const float om = 1.0f - 0.99f;
    float bias = 1.0f - powf(0.99f, countp[0] + 1.0f);
    float Nv   = (0.99f * Shc[0] + 0.01f * 16384.0f) / bias;
    float avgk = (hc[k] * 0.99f + om * counts[k]) / bias;
    float ccv  = ((avgk + 1e-5f) / (Nv + 0.04096f)) * Nv;
    size_t b = (size_t)k * D;
    cbn[b + tid]       = ((hdw[b + tid]       * 0.99f + om * a0) / bias) / ccv;
    cbn[b + tid + 256] = ((hdw[b + tid + 256] * 0.99f + om * a1) / bias) / ccv;
}

// 2 rows per block, float4 loads/stores (4x fewer memory instructions).
// Per-element arithmetic identical; only the loss-partial reduction order
// changes (tolerance-safe, finalize accumulates in double anyway).
__global__ __launch_bounds__(256) void gather_kernel(
    const float* __restrict__ x, const unsigned long long* __restrict__ keys,
    const float* __restrict__ cbn, float* __restrict__ outq,
    float* __restrict__ partial)
{
    __shared__ float sm[256];
    int t    = threadIdx.x;
    int rloc = t >> 7;                       // 0..1
    int ci   = t & 127;                      // float4 index within row
    int row  = blockIdx.x * 2 + rloc;
    int k    = (int)(keys[row] & 0xFFFULL);
    const float4* xv4 = (const float4*)(x   + (size_t)row * D);
    const float4* cv4 = (const float4*)(cbn + (size_t)k   * D);
    float4*       ov4 = (float4*)(outq + (size_t)row * D);
    float4 xv = xv4[ci];
    float4 qv = cv4[ci];
    float4 quant;
    quant.x = xv.x + (qv.x - xv.x);
    quant.y = xv.y + (qv.y - xv.y);
    quant.z = xv.z + (qv.z - xv.z);
    quant.w = xv.w + (qv.w - xv.w);
    ov4[ci] = quant;
    float dx = xv.x - quant.x, dy = xv.y - quant.y;
    float dz = xv.z - quant.z, dw = xv.w - quant.w;
    float local = 0.f;
    local = fmaf(dx, dx, local);
    local = fmaf(dy, dy, local);
    local = fmaf(dz, dz, local);
    local = fmaf(dw, dw, local);
    sm[t] = local;
    __syncthreads();
    for (int s = 64; s > 0; s >>= 1) {
        if ((t & 127) < s) sm[t] += sm[t + s];
        __syncthreads();
    }
    if (ci == 0) {
        partial[row] = sm[rloc * 128];
        outq[8388609 + row] = (float)k;
    }
}

__global__ __launch_bounds__(256) void finalize_kernel(
    const float* __restrict__ partial, float* __restrict__ out)
{
    __shared__ double sm[256];
    int tid = threadIdx.x;
    double s = 0.0;
#pragma unroll
    for (int j = 0; j < 64; ++j) s += (double)partial[tid + j * 256];
    sm[tid] = s;
    __syncthreads();
    for (int st = 128; st > 0; st >>= 1) {
        if (tid < st) sm[tid] += sm[tid + st];
        __syncthreads();
    }
    if (tid == 0) out[8388608] = (float)(0.5 * sm[0] / 8388608.0);
}

// ================= launcher ================================================

extern "C" void kernel_launch(void* const* d_in, const int* in_sizes, int n_in,
                              void* d_out, int out_size, void* d_ws, size_t ws_size,
                              hipStream_t stream)
{
    const float* x   = (const float*)d_in[0];
    const float* cb  = (const float*)d_in[1];
    const float* hc  = (const float*)d_in[2];
    const float* hdw = (const float*)d_in[3];
    const float* cnt = (const float*)d_in[4];
    float* out = (float*)d_out;

    char* ws = (char*)d_ws;
    float*  c2     = (float*)(ws + OFF_C2);
    float*  x2     = (float*)(ws + OFF_X2);
    float*  counts = (float*)(ws + OFF_CNT);
    float*  Shc    = (float*)(ws + OFF_SCAL + 16);
    unsigned short* idx16 = (unsigned short*)(ws + OFF_IDX16);
    unsigned long long* keys = (unsigned long long*)(ws + OFF_KEYS);
    float*  partial= (float*)(ws + OFF_X2);   // x2 dead after rescore

    // zero x2 (atomically accumulated in primary) + counts + avgc region + scal
    hipMemsetAsync(ws + OFF_X2, 0, (96 << 10) + 32, stream);

    const bool primary = ws_size >= ((size_t)10 << 20);
    float* cbn;
    if (primary) {
        // c2 rows (bit-exact) + S_hc; x2 fused into split_interleave
        rowsq_all<<<K + 1, 64, 0, stream>>>(x, cb, hc, x2, c2, Shc);

        // xh'+xl' streams = 2*8*16384*128 B = 33,554,432 B: exactly d_out's
        // quantized region; gather overwrites at the end. cb' (hi) = 4.19 MB in ws.
        unsigned short* gxp = (unsigned short*)d_out;
        unsigned short* gcp = (unsigned short*)(ws + OFF_CBP);
        unsigned short* cand = (unsigned short*)(ws + OFF_CAND);
        cbn = (float*)(ws + OFF_CBP);   // reuses cb' after argmin

        split_interleave<<<5120, 256, 0, stream>>>(x, cb, gxp, gcp, x2);
        argmin_mfma<<<dim3(BL / 128, 4), 256, 0, stream>>>(gxp, gcp, x2, c2, cand);
        rescore_kernel<<<(BL * 8) / 256, 256, 0, stream>>>(x, cb, x2, c2, cand, keys,
                                                           counts, idx16);
    } else {
        // fallback: x2 from rowsq blocks (original bit-exact path)
        rowsq_all<<<K + 1 + BL, 64, 0, stream>>>(x, cb, hc, x2, c2, Shc);
        cbn = (float*)(ws + OFF_CBN_FB);
        hipMemsetAsync(ws + OFF_KEYS, 0xFF, BL * 8, stream);
        argmin_fb<<<dim3(BL / 64, 4), 256, 0, stream>>>(x, cb, x2, c2, keys);
        count_kernel<<<BL / 256, 256, 0, stream>>>(keys, counts, idx16);
    }

    code_update_kernel<<<K, 256, 0, stream>>>(x, idx16, hdw, hc, counts, Shc, cnt, cbn);
    gather_kernel<<<BL / 2, 256, 0, stream>>>(x, keys, cbn, out, partial);
    finalize_kernel<<<1, 256, 0, stream>>>(partial, out);
}